// Round 3
// baseline (326.746 us; speedup 1.0000x reference)
//
#include <hip/hip_runtime.h>
#include <math.h>

// DCGRU cell, N=8192, B=1, D_IN=2, UNITS=64, K=2 -> F=66, M=3.
// adj_mx @ v == adj^T @ (dinv*v) + (dinv*v)   (adj2 = adj + I folded in)
// Heavy GEMMs on bf16 MFMA (v_mfma_f32_16x16x32_bf16), f32 accum.
// adjF: bf16 adj^T in fragment order: frag(mt,kb) = 1KB, element (lane l, j)
//   = adj[kb*32 + 8*(l>>4) + j][mt*16 + (l&15)]
// UtF:  bf16 U^T in fragment order: frag(kb,nt), element (l,j)
//   = U[kb*32 + 8*(l>>4) + j][nt*16 + (l&15)]   (cols 66..79 = 0 pad)
// ws layout ends ..., UtF, adjF, UG so the GEMM's branchless +1-frag
// prefetch over-read lands in the following buffer (harmless).

typedef __attribute__((ext_vector_type(8))) short short8v;
typedef __attribute__((ext_vector_type(4))) float f32x4;

constexpr int NN   = 8192;
constexpr int CST  = 80;                   // padded f32 row stride
constexpr int KBT  = 256;                  // k-blocks of 32
constexpr int SPLITS = 8;
constexpr int KB_PER = KBT / SPLITS;       // 32
constexpr size_t NS = (size_t)NN * CST;    // 655360 floats per matrix

static __device__ __forceinline__ ushort f2bf(float x) {
  union { float f; unsigned u; } c; c.f = x;
  unsigned u = c.u;
  u += 0x7fffu + ((u >> 16) & 1u);         // RNE
  return (ushort)(u >> 16);
}

static __device__ __forceinline__ void mfma_b16(f32x4& acc, short8v a, short8v b) {
  asm("v_mfma_f32_16x16x32_bf16 %0, %1, %2, %0" : "+v"(acc) : "v"(a), "v"(b));
}

// ---------------- adj -> bf16 fragment-order transpose + row-sum partials ----
__global__ __launch_bounds__(256) void k_conv(const float* __restrict__ adj,
                                              ushort* __restrict__ adjF,
                                              float* __restrict__ dpart) {
  __shared__ float tile[32][132];
  const int kb = blockIdx.x;               // 0..255 : k rows kb*32..+31
  const int half = blockIdx.y;             // 0..1   : i columns half*4096..
  const int tid = threadIdx.x;
  const int kr = tid >> 3;                 // 0..31 row in band
  const int c16 = (tid & 7) * 16;          // col offset in 128-chunk
  const int f = tid >> 6, l = tid & 63;
  const float* src = adj + ((size_t)kb * 32 + kr) * NN + half * 4096;
  float rs = 0.f;
  for (int ch = 0; ch < 32; ++ch) {
    float4 v0 = *(const float4*)(src + ch * 128 + c16);
    float4 v1 = *(const float4*)(src + ch * 128 + c16 + 4);
    float4 v2 = *(const float4*)(src + ch * 128 + c16 + 8);
    float4 v3 = *(const float4*)(src + ch * 128 + c16 + 12);
    rs += (v0.x + v0.y + v0.z + v0.w) + (v1.x + v1.y + v1.z + v1.w)
        + (v2.x + v2.y + v2.z + v2.w) + (v3.x + v3.y + v3.z + v3.w);
    *(float4*)&tile[kr][c16]      = v0;
    *(float4*)&tile[kr][c16 + 4]  = v1;
    *(float4*)&tile[kr][c16 + 8]  = v2;
    *(float4*)&tile[kr][c16 + 12] = v3;
    __syncthreads();
#pragma unroll
    for (int h = 0; h < 2; ++h) {
      int fl = f + h * 4;                  // 0..7 fragment within chunk
      int mt = half * 256 + ch * 8 + fl;
      short8v o;
#pragma unroll
      for (int j = 0; j < 8; ++j)
        o[j] = (short)f2bf(tile[8 * (l >> 4) + j][fl * 16 + (l & 15)]);
      *(short8v*)(adjF + ((size_t)mt * KBT + kb) * 512 + l * 8) = o;
    }
    __syncthreads();
  }
  rs += __shfl_down(rs, 4);
  rs += __shfl_down(rs, 2);
  rs += __shfl_down(rs, 1);
  if ((tid & 7) == 0) dpart[half * NN + kb * 32 + kr] = rs;
}

// ---------------- build: dinv + X0 (f32 [N][80]) + XS0 + UtF(XS0) ------------
__global__ __launch_bounds__(256) void k_build(const float* __restrict__ hx,
                                               const float* __restrict__ inp,
                                               const float* __restrict__ dpart,
                                               float* __restrict__ dinv,
                                               float* __restrict__ X0,
                                               float* __restrict__ XS0,
                                               ushort* __restrict__ UtF) {
  __shared__ float dv_s[32];
  const int n0 = blockIdx.x * 32;
  const int tid = threadIdx.x;
  if (tid < 32) {
    int n = n0 + tid;
    float dv = 1.f / (dpart[n] + dpart[NN + n] + 1.f);
    dv_s[tid] = dv;
    dinv[n] = dv;
  }
  __syncthreads();
  for (int p = tid; p < 32 * 20; p += 256) {
    int nl = p / 20, c4 = (p % 20) * 4;
    int n = n0 + nl;
    float dv = dv_s[nl];
    float v[4];
#pragma unroll
    for (int j = 0; j < 4; ++j) {
      int c = c4 + j;
      v[j] = (c < 64) ? hx[n * 64 + c] : (c < 66 ? inp[n * 2 + (c - 64)] : 0.f);
    }
    size_t o = (size_t)n * CST + c4;
    *(float4*)(X0 + o)  = make_float4(v[0], v[1], v[2], v[3]);
    *(float4*)(XS0 + o) = make_float4(dv * v[0], dv * v[1], dv * v[2], dv * v[3]);
  }
  for (int p = tid; p < 5 * 64; p += 256) {
    int nt = p >> 6, l = p & 63;
    short8v o8;
#pragma unroll
    for (int j = 0; j < 8; ++j) {
      int nloc = 8 * (l >> 4) + j;
      int n = n0 + nloc;
      int c = nt * 16 + (l & 15);
      float v = (c < 64) ? hx[n * 64 + c] : (c < 66 ? inp[n * 2 + (c - 64)] : 0.f);
      o8[j] = (short)f2bf(v * dv_s[nloc]);
    }
    *(short8v*)(UtF + ((size_t)blockIdx.x * 5 + nt) * 512 + l * 8) = o8;
  }
}

// ---------------- MFMA GEMM: P[split] = adj^T-chunk @ U ----------------------
// Explicit 2-stage software pipeline: loads for step k+1 issued before the
// MFMAs of step k. Branchless: final prefetch over-reads one frag into the
// buffer that follows (adjF->UG, UtF->adjF) — never consumed.
__global__ __launch_bounds__(256) void k_gemm(const ushort* __restrict__ adjF,
                                              const ushort* __restrict__ UtF,
                                              float* __restrict__ P) {
  const int w = threadIdx.x >> 6, l = threadIdx.x & 63;
  const int mt = blockIdx.x * 4 + w;             // 0..511
  const int kb0 = blockIdx.y * KB_PER;
  f32x4 acc[5];
#pragma unroll
  for (int nt = 0; nt < 5; ++nt) acc[nt] = (f32x4){0.f, 0.f, 0.f, 0.f};
  const ushort* ap = adjF + ((size_t)mt * KBT + kb0) * 512 + l * 8;
  const ushort* bp = UtF + (size_t)kb0 * 5 * 512 + l * 8;

  short8v aE, aO, bE[5], bO[5];
  aE = *(const short8v*)(ap);
#pragma unroll
  for (int nt = 0; nt < 5; ++nt) bE[nt] = *(const short8v*)(bp + nt * 512);

  for (int kb = 0; kb < KB_PER; kb += 2) {
    aO = *(const short8v*)(ap + (size_t)(kb + 1) * 512);
#pragma unroll
    for (int nt = 0; nt < 5; ++nt)
      bO[nt] = *(const short8v*)(bp + (size_t)((kb + 1) * 5 + nt) * 512);
#pragma unroll
    for (int nt = 0; nt < 5; ++nt) mfma_b16(acc[nt], aE, bE[nt]);
    aE = *(const short8v*)(ap + (size_t)(kb + 2) * 512);
#pragma unroll
    for (int nt = 0; nt < 5; ++nt)
      bE[nt] = *(const short8v*)(bp + (size_t)((kb + 2) * 5 + nt) * 512);
#pragma unroll
    for (int nt = 0; nt < 5; ++nt) mfma_b16(acc[nt], aO, bO[nt]);
  }
  asm volatile("s_nop 7\n\ts_nop 7\n\ts_nop 7" ::: "memory");  // MFMA->read hazard guard
  // D row = (l>>4)*4 + r, col = l&15
  float* Pp = P + (size_t)blockIdx.y * NS + ((size_t)mt * 16 + (l >> 4) * 4) * CST + (l & 15);
#pragma unroll
  for (int nt = 0; nt < 5; ++nt)
#pragma unroll
    for (int r = 0; r < 4; ++r)
      Pp[(size_t)r * CST + nt * 16] = acc[nt][r];
}

// ---------------- epilogue A: X1 = sumP + XSin ; XS1 = dinv*X1 ; UtF(XS1) ----
__global__ __launch_bounds__(512) void k_epiA(const float* __restrict__ P,
                                              const float* __restrict__ XSin,
                                              const float* __restrict__ dinv,
                                              float* __restrict__ X1,
                                              float* __restrict__ XS1,
                                              ushort* __restrict__ UtF) {
  __shared__ float xs[32][84];
  const int n0 = blockIdx.x * 32;
  const int tid = threadIdx.x;
  for (int p = tid; p < 32 * 20; p += 512) {
    int nl = p / 20, c4 = (p % 20) * 4;
    int n = n0 + nl;
    size_t o = (size_t)n * CST + c4;
    float4 s = *(const float4*)(XSin + o);
#pragma unroll
    for (int sp = 0; sp < SPLITS; ++sp) {
      float4 t = *(const float4*)(P + (size_t)sp * NS + o);
      s.x += t.x; s.y += t.y; s.z += t.z; s.w += t.w;
    }
    *(float4*)(X1 + o) = s;
    float dv = dinv[n];
    float4 z = make_float4(dv * s.x, dv * s.y, dv * s.z, dv * s.w);
    *(float4*)(XS1 + o) = z;
    *(float4*)&xs[nl][c4] = z;
  }
  __syncthreads();
  for (int p = tid; p < 5 * 64; p += 512) {
    int nt = p >> 6, l = p & 63;
    short8v o8;
#pragma unroll
    for (int j = 0; j < 8; ++j)
      o8[j] = (short)f2bf(xs[8 * (l >> 4) + j][nt * 16 + (l & 15)]);
    *(short8v*)(UtF + ((size_t)blockIdx.x * 5 + nt) * 512 + l * 8) = o8;
  }
}

// ---------------- gates (epiB fused): X2 inline; sigmoid matmul --------------
__global__ __launch_bounds__(256) void k_gates(const float* __restrict__ P,
    const float* __restrict__ XS1,
    const float* __restrict__ X0, const float* __restrict__ X1,
    const float* __restrict__ w_ru, const float* __restrict__ b_ru,
    const float* __restrict__ hx, const float* __restrict__ inp,
    const float* __restrict__ dinv,
    float* __restrict__ X0w, float* __restrict__ XS0w,
    ushort* __restrict__ UtF, float* __restrict__ UG) {
  __shared__ float xr[3][32][68];
  __shared__ float rhq[32][64];
  const int n0 = blockIdx.x * 32;
  const int tid = threadIdx.x;
  for (int p = tid; p < 32 * 17; p += 256) {
    int nl = p / 17, c4 = (p % 17) * 4;
    size_t o = (size_t)(n0 + nl) * CST + c4;
    float4 x0 = *(const float4*)(X0 + o);
    float4 s  = *(const float4*)(XS1 + o);
#pragma unroll
    for (int sp = 0; sp < SPLITS; ++sp) {
      float4 t = *(const float4*)(P + (size_t)sp * NS + o);
      s.x += t.x; s.y += t.y; s.z += t.z; s.w += t.w;
    }
    *(float4*)&xr[0][nl][c4] = x0;
    *(float4*)&xr[1][nl][c4] = *(const float4*)(X1 + o);
    *(float4*)&xr[2][nl][c4] = make_float4(2.f * s.x - x0.x, 2.f * s.y - x0.y,
                                           2.f * s.z - x0.z, 2.f * s.w - x0.w);
  }
  __syncthreads();
  const int nl = tid >> 3, og = tid & 7, o0 = og * 16;
  float acc[16];
#pragma unroll
  for (int j = 0; j < 16; ++j) acc[j] = b_ru[o0 + j];
  for (int c = 0; c < 66; ++c) {
    int f = (c < 64) ? (c + 2) : (c - 64);
    const float* wr = w_ru + (size_t)(f * 3) * 128 + o0;
#pragma unroll
    for (int m = 0; m < 3; ++m) {
      float xv = xr[m][nl][c];
      float wl[16];
      *(float4*)(wl)      = *(const float4*)(wr + m * 128);
      *(float4*)(wl + 4)  = *(const float4*)(wr + m * 128 + 4);
      *(float4*)(wl + 8)  = *(const float4*)(wr + m * 128 + 8);
      *(float4*)(wl + 12) = *(const float4*)(wr + m * 128 + 12);
#pragma unroll
      for (int j = 0; j < 16; ++j) acc[j] += xv * wl[j];
    }
  }
  const int n = n0 + nl;
  const float dv = dinv[n];
  if (og < 4) {
#pragma unroll
    for (int j = 0; j < 16; ++j) {
      int o = o0 + j;
      float r = 1.f / (1.f + expf(-acc[j]));
      float rh = r * hx[n * 64 + o];
      X0w[(size_t)n * CST + o] = rh;
      float srh = dv * rh;
      XS0w[(size_t)n * CST + o] = srh;
      rhq[nl][o] = srh;
    }
  } else {
#pragma unroll
    for (int j = 0; j < 16; ++j)
      UG[n * 64 + (o0 - 64) + j] = 1.f / (1.f + expf(-acc[j]));
  }
  __syncthreads();
  for (int p = tid; p < 5 * 64; p += 256) {
    int nt = p >> 6, l = p & 63;
    short8v o8;
#pragma unroll
    for (int j = 0; j < 8; ++j) {
      int nloc = 8 * (l >> 4) + j;
      int nn = n0 + nloc;
      int c = nt * 16 + (l & 15);
      float v;
      if (c < 64)      v = rhq[nloc][c];
      else if (c < 66) v = dinv[nn] * inp[nn * 2 + (c - 64)];
      else             v = 0.f;
      o8[j] = (short)f2bf(v);
    }
    *(short8v*)(UtF + ((size_t)blockIdx.x * 5 + nt) * 512 + l * 8) = o8;
  }
}

// ---------------- final (epiB fused): candidate + output ---------------------
__global__ __launch_bounds__(256) void k_final(const float* __restrict__ P,
    const float* __restrict__ XS1,
    const float* __restrict__ X0, const float* __restrict__ X1,
    const float* __restrict__ w_c, const float* __restrict__ b_c,
    const float* __restrict__ hx, const float* __restrict__ UG,
    float* __restrict__ out) {
  __shared__ float xr[3][16][68];
  const int n0 = blockIdx.x * 16;
  const int tid = threadIdx.x;
  for (int p = tid; p < 16 * 17; p += 256) {
    int nl = p / 17, c4 = (p % 17) * 4;
    size_t o = (size_t)(n0 + nl) * CST + c4;
    float4 x0 = *(const float4*)(X0 + o);
    float4 s  = *(const float4*)(XS1 + o);
#pragma unroll
    for (int sp = 0; sp < SPLITS; ++sp) {
      float4 t = *(const float4*)(P + (size_t)sp * NS + o);
      s.x += t.x; s.y += t.y; s.z += t.z; s.w += t.w;
    }
    *(float4*)&xr[0][nl][c4] = x0;
    *(float4*)&xr[1][nl][c4] = *(const float4*)(X1 + o);
    *(float4*)&xr[2][nl][c4] = make_float4(2.f * s.x - x0.x, 2.f * s.y - x0.y,
                                           2.f * s.z - x0.z, 2.f * s.w - x0.w);
  }
  __syncthreads();
  const int nl = tid >> 4, ot = tid & 15, o0 = ot * 4;
  float acc[4];
#pragma unroll
  for (int j = 0; j < 4; ++j) acc[j] = b_c[o0 + j];
  for (int c = 0; c < 66; ++c) {
    int f = (c < 64) ? (c + 2) : (c - 64);
#pragma unroll
    for (int m = 0; m < 3; ++m) {
      float xv = xr[m][nl][c];
      float wl[4];
      *(float4*)(wl) = *(const float4*)(w_c + (size_t)(f * 3 + m) * 64 + o0);
#pragma unroll
      for (int j = 0; j < 4; ++j) acc[j] += xv * wl[j];
    }
  }
  const int n = n0 + nl;
#pragma unroll
  for (int j = 0; j < 4; ++j) {
    int o = o0 + j;
    float cc = tanhf(acc[j]);
    float u = UG[n * 64 + o];
    float h = hx[n * 64 + o];
    out[n * 64 + o] = u * h + (1.f - u) * cc;
  }
}

// ---------------- launcher ----------------------------------------------------
extern "C" void kernel_launch(void* const* d_in, const int* in_sizes, int n_in,
                              void* d_out, int out_size, void* d_ws, size_t ws_size,
                              hipStream_t stream) {
  const float* inp  = (const float*)d_in[0];
  const float* hx   = (const float*)d_in[1];
  const float* adj  = (const float*)d_in[2];
  const float* w_ru = (const float*)d_in[3];
  const float* b_ru = (const float*)d_in[4];
  const float* w_c  = (const float*)d_in[5];
  const float* b_c  = (const float*)d_in[6];
  float* out = (float*)d_out;

  float* ws    = (float*)d_ws;
  float* dinv  = ws;                       // 8192
  float* dpart = ws + 8192;                // 2*8192
  float* X0    = ws + 24576;               // [N][80] each
  float* XS0   = X0 + NS;
  float* X1    = XS0 + NS;
  float* XS1   = X1 + NS;
  float* P     = XS1 + NS;                 // SPLITS * NS
  ushort* UtF  = (ushort*)(P + (size_t)SPLITS * NS);       // 1.25 MB
  ushort* adjF = UtF + (size_t)KBT * 5 * 512;              // 128 MB
  float* UG    = (float*)(adjF + (size_t)512 * KBT * 512); // [N][64] (also OOB pad)

  dim3 cg(KBT, 2);
  dim3 gg(NN / 64, SPLITS);

  k_conv <<<cg, 256, 0, stream>>>(adj, adjF, dpart);
  k_build<<<NN / 32, 256, 0, stream>>>(hx, inp, dpart, dinv, X0, XS0, UtF);

  // gconv 1 (gates)
  k_gemm <<<gg, 256, 0, stream>>>(adjF, UtF, P);
  k_epiA <<<NN / 32, 512, 0, stream>>>(P, XS0, dinv, X1, XS1, UtF);
  k_gemm <<<gg, 256, 0, stream>>>(adjF, UtF, P);
  k_gates<<<NN / 32, 256, 0, stream>>>(P, XS1, X0, X1, w_ru, b_ru, hx, inp, dinv,
                                       X0, XS0, UtF, UG);

  // gconv 2 (candidate)
  k_gemm <<<gg, 256, 0, stream>>>(adjF, UtF, P);
  k_epiA <<<NN / 32, 512, 0, stream>>>(P, XS0, dinv, X1, XS1, UtF);
  k_gemm <<<gg, 256, 0, stream>>>(adjF, UtF, P);
  k_final<<<NN / 16, 256, 0, stream>>>(P, XS1, X0, X1, w_c, b_c, hx, UG, out);
}

// Round 5
// 296.340 us; speedup vs baseline: 1.1026x; 1.1026x over previous
//
#include <hip/hip_runtime.h>
#include <math.h>

// DCGRU cell, N=8192, B=1, D_IN=2, UNITS=64, K=2 -> F=66, M=3.
// adj_mx @ v == adj^T @ (dinv*v) + (dinv*v)   (adj2 = adj + I folded in)
// Heavy GEMMs on bf16 MFMA (v_mfma_f32_16x16x32_bf16), f32 accum.
// adjF: bf16 adj^T in fragment order: frag(mt,kb) = 1KB, element (lane l, j)
//   = adj[kb*32 + 8*(l>>4) + j][mt*16 + (l&15)]
// UtF:  bf16 U^T in fragment order: frag(kb,nt), element (l,j)
//   = U[kb*32 + 8*(l>>4) + j][nt*16 + (l&15)]   (cols 66..79 = 0 pad)
// ws layout ends ..., UtF, adjF, UG so the GEMM's branchless +1-frag
// prefetch over-read lands in the following buffer (harmless).

typedef __attribute__((ext_vector_type(8))) short short8v;
typedef __attribute__((ext_vector_type(4))) float f32x4;

constexpr int NN   = 8192;
constexpr int CST  = 80;                   // padded f32 row stride
constexpr int KBT  = 256;                  // k-blocks of 32
constexpr int SPLITS = 4;
constexpr int KB_PER = KBT / SPLITS;       // 64
constexpr int MCH  = 4;                    // k_conv m-chunks (blockIdx.y)
constexpr size_t NS = (size_t)NN * CST;    // 655360 floats per matrix

static __device__ __forceinline__ ushort f2bf(float x) {
  union { float f; unsigned u; } c; c.f = x;
  unsigned u = c.u;
  u += 0x7fffu + ((u >> 16) & 1u);         // RNE
  return (ushort)(u >> 16);
}

static __device__ __forceinline__ void mfma_b16(f32x4& acc, short8v a, short8v b) {
  asm("v_mfma_f32_16x16x32_bf16 %0, %1, %2, %0" : "+v"(acc) : "v"(a), "v"(b));
}

// ---------------- adj -> bf16 fragment transpose + row-sum partials ----------
// Block: 32 k-rows (kb) x 2048 m-cols (mc), 16 chunks of 32x128.
// Coalesced loads (2x512B segments/inst), double-buffered LDS (1 barrier per
// chunk), column-rotation swizzle col' = (c + 8*(r>>3)) & 127 so transpose
// reads are 2-way (free) instead of 4-way conflicted.
__global__ __launch_bounds__(256, 4) void k_conv(const float* __restrict__ adj,
                                                 ushort* __restrict__ adjF,
                                                 float* __restrict__ dpart) {
  __shared__ float tile[2][32][132];
  const int kb = blockIdx.x, mc = blockIdx.y;
  const int tid = threadIdx.x;
  const int l = tid & 63, w = tid >> 6;
  const int rg = tid >> 5;                 // 0..7 row group
  const int cb = (tid & 31) * 4;           // col base within chunk
  const float* src = adj + ((size_t)kb * 32 + rg) * NN + (size_t)mc * 2048 + cb;
  float rs[4] = {0.f, 0.f, 0.f, 0.f};
  float4 vA[4], vB[4];

#pragma unroll
  for (int i = 0; i < 4; ++i)
    vA[i] = *(const float4*)(src + (size_t)(8 * i) * NN);

#define CONV_BODY(CH, BUF, VC, VN)                                             \
  {                                                                            \
    const int ch_ = (CH);                                                      \
    _Pragma("unroll") for (int i = 0; i < 4; ++i) {                            \
      int r = rg + 8 * i;                                                      \
      int colp = (cb + 8 * i) & 127;                                           \
      *(float4*)&tile[BUF][r][colp] = VC[i];                                   \
      rs[i] += (VC[i].x + VC[i].y) + (VC[i].z + VC[i].w);                      \
    }                                                                          \
    if (ch_ < 15) {                                                            \
      _Pragma("unroll") for (int i = 0; i < 4; ++i)                            \
          VN[i] = *(const float4*)(src + (size_t)(8 * i) * NN + (ch_ + 1) * 128); \
    }                                                                          \
    __syncthreads();                                                           \
    _Pragma("unroll") for (int h = 0; h < 2; ++h) {                            \
      int fl = w + 4 * h;                                                      \
      int mt = mc * 128 + ch_ * 8 + fl;                                        \
      short8v o;                                                               \
      _Pragma("unroll") for (int j = 0; j < 8; ++j) {                          \
        int r = 8 * (l >> 4) + j;                                              \
        int colp = (fl * 16 + (l & 15) + 8 * (l >> 4)) & 127;                  \
        o[j] = (short)f2bf(tile[BUF][r][colp]);                                \
      }                                                                        \
      *(short8v*)(adjF + ((size_t)mt * KBT + kb) * 512 + l * 8) = o;           \
    }                                                                          \
  }

  for (int cp = 0; cp < 8; ++cp) {
    CONV_BODY(2 * cp,     0, vA, vB);
    CONV_BODY(2 * cp + 1, 1, vB, vA);
  }
#undef CONV_BODY

#pragma unroll
  for (int i = 0; i < 4; ++i) {
#pragma unroll
    for (int m = 16; m >= 1; m >>= 1) rs[i] += __shfl_xor(rs[i], m);
  }
  if ((tid & 31) == 0) {
#pragma unroll
    for (int i = 0; i < 4; ++i)
      dpart[(size_t)mc * NN + kb * 32 + 8 * i + rg] = rs[i];
  }
}

// ---------------- build: dinv + X0 (f32 [N][80]) + XS0 + UtF(XS0) ------------
__global__ __launch_bounds__(256) void k_build(const float* __restrict__ hx,
                                               const float* __restrict__ inp,
                                               const float* __restrict__ dpart,
                                               float* __restrict__ dinv,
                                               float* __restrict__ X0,
                                               float* __restrict__ XS0,
                                               ushort* __restrict__ UtF) {
  __shared__ float dv_s[32];
  const int n0 = blockIdx.x * 32;
  const int tid = threadIdx.x;
  if (tid < 32) {
    int n = n0 + tid;
    float dv = 1.f / (dpart[n] + dpart[NN + n] + dpart[2 * NN + n] +
                      dpart[3 * NN + n] + 1.f);
    dv_s[tid] = dv;
    dinv[n] = dv;
  }
  __syncthreads();
  for (int p = tid; p < 32 * 20; p += 256) {
    int nl = p / 20, c4 = (p % 20) * 4;
    int n = n0 + nl;
    float dv = dv_s[nl];
    float v[4];
#pragma unroll
    for (int j = 0; j < 4; ++j) {
      int c = c4 + j;
      v[j] = (c < 64) ? hx[n * 64 + c] : (c < 66 ? inp[n * 2 + (c - 64)] : 0.f);
    }
    size_t o = (size_t)n * CST + c4;
    *(float4*)(X0 + o)  = make_float4(v[0], v[1], v[2], v[3]);
    *(float4*)(XS0 + o) = make_float4(dv * v[0], dv * v[1], dv * v[2], dv * v[3]);
  }
  for (int p = tid; p < 5 * 64; p += 256) {
    int nt = p >> 6, l = p & 63;
    short8v o8;
#pragma unroll
    for (int j = 0; j < 8; ++j) {
      int nloc = 8 * (l >> 4) + j;
      int n = n0 + nloc;
      int c = nt * 16 + (l & 15);
      float v = (c < 64) ? hx[n * 64 + c] : (c < 66 ? inp[n * 2 + (c - 64)] : 0.f);
      o8[j] = (short)f2bf(v * dv_s[nloc]);
    }
    *(short8v*)(UtF + ((size_t)blockIdx.x * 5 + nt) * 512 + l * 8) = o8;
  }
}

// ---------------- MFMA GEMM: P[split] = adj^T-chunk @ U ----------------------
// 2-stage software pipeline; branchless final prefetch over-reads one frag
// into the following buffer (adjF->UG, UtF->adjF) — never consumed.
__global__ __launch_bounds__(256, 2) void k_gemm(const ushort* __restrict__ adjF,
                                                 const ushort* __restrict__ UtF,
                                                 float* __restrict__ P) {
  const int w = threadIdx.x >> 6, l = threadIdx.x & 63;
  const int mt = blockIdx.x * 4 + w;             // 0..511
  const int kb0 = blockIdx.y * KB_PER;
  f32x4 acc[5];
#pragma unroll
  for (int nt = 0; nt < 5; ++nt) acc[nt] = (f32x4){0.f, 0.f, 0.f, 0.f};
  const ushort* ap = adjF + ((size_t)mt * KBT + kb0) * 512 + l * 8;
  const ushort* bp = UtF + (size_t)kb0 * 5 * 512 + l * 8;

  short8v aE, aO, bE[5], bO[5];
  aE = *(const short8v*)(ap);
#pragma unroll
  for (int nt = 0; nt < 5; ++nt) bE[nt] = *(const short8v*)(bp + nt * 512);

  for (int kb = 0; kb < KB_PER; kb += 2) {
    aO = *(const short8v*)(ap + (size_t)(kb + 1) * 512);
#pragma unroll
    for (int nt = 0; nt < 5; ++nt)
      bO[nt] = *(const short8v*)(bp + (size_t)((kb + 1) * 5 + nt) * 512);
#pragma unroll
    for (int nt = 0; nt < 5; ++nt) mfma_b16(acc[nt], aE, bE[nt]);
    aE = *(const short8v*)(ap + (size_t)(kb + 2) * 512);
#pragma unroll
    for (int nt = 0; nt < 5; ++nt)
      bE[nt] = *(const short8v*)(bp + (size_t)((kb + 2) * 5 + nt) * 512);
#pragma unroll
    for (int nt = 0; nt < 5; ++nt) mfma_b16(acc[nt], aO, bO[nt]);
  }
  asm volatile("s_nop 7\n\ts_nop 7\n\ts_nop 7" ::: "memory");
  // D row = (l>>4)*4 + r, col = l&15
  float* Pp = P + (size_t)blockIdx.y * NS + ((size_t)mt * 16 + (l >> 4) * 4) * CST + (l & 15);
#pragma unroll
  for (int nt = 0; nt < 5; ++nt)
#pragma unroll
    for (int r = 0; r < 4; ++r)
      Pp[(size_t)r * CST + nt * 16] = acc[nt][r];
}

// ---------------- epilogue A: X1 = sumP + XSin ; XS1 = dinv*X1 ; UtF(XS1) ----
__global__ __launch_bounds__(512) void k_epiA(const float* __restrict__ P,
                                              const float* __restrict__ XSin,
                                              const float* __restrict__ dinv,
                                              float* __restrict__ X1,
                                              float* __restrict__ XS1,
                                              ushort* __restrict__ UtF) {
  __shared__ float xs[32][84];
  const int n0 = blockIdx.x * 32;
  const int tid = threadIdx.x;
  for (int p = tid; p < 32 * 20; p += 512) {
    int nl = p / 20, c4 = (p % 20) * 4;
    int n = n0 + nl;
    size_t o = (size_t)n * CST + c4;
    float4 s = *(const float4*)(XSin + o);
#pragma unroll
    for (int sp = 0; sp < SPLITS; ++sp) {
      float4 t = *(const float4*)(P + (size_t)sp * NS + o);
      s.x += t.x; s.y += t.y; s.z += t.z; s.w += t.w;
    }
    *(float4*)(X1 + o) = s;
    float dv = dinv[n];
    float4 z = make_float4(dv * s.x, dv * s.y, dv * s.z, dv * s.w);
    *(float4*)(XS1 + o) = z;
    *(float4*)&xs[nl][c4] = z;
  }
  __syncthreads();
  for (int p = tid; p < 5 * 64; p += 512) {
    int nt = p >> 6, l = p & 63;
    short8v o8;
#pragma unroll
    for (int j = 0; j < 8; ++j)
      o8[j] = (short)f2bf(xs[8 * (l >> 4) + j][nt * 16 + (l & 15)]);
    *(short8v*)(UtF + ((size_t)blockIdx.x * 5 + nt) * 512 + l * 8) = o8;
  }
}

// ---------------- gates (epiB fused): X2 inline; sigmoid matmul --------------
__global__ __launch_bounds__(256) void k_gates(const float* __restrict__ P,
    const float* __restrict__ XS1,
    const float* __restrict__ X0, const float* __restrict__ X1,
    const float* __restrict__ w_ru, const float* __restrict__ b_ru,
    const float* __restrict__ hx, const float* __restrict__ inp,
    const float* __restrict__ dinv,
    float* __restrict__ X0w, float* __restrict__ XS0w,
    ushort* __restrict__ UtF, float* __restrict__ UG) {
  __shared__ float xr[3][32][68];
  __shared__ float rhq[32][64];
  const int n0 = blockIdx.x * 32;
  const int tid = threadIdx.x;
  for (int p = tid; p < 32 * 17; p += 256) {
    int nl = p / 17, c4 = (p % 17) * 4;
    size_t o = (size_t)(n0 + nl) * CST + c4;
    float4 x0 = *(const float4*)(X0 + o);
    float4 s  = *(const float4*)(XS1 + o);
#pragma unroll
    for (int sp = 0; sp < SPLITS; ++sp) {
      float4 t = *(const float4*)(P + (size_t)sp * NS + o);
      s.x += t.x; s.y += t.y; s.z += t.z; s.w += t.w;
    }
    *(float4*)&xr[0][nl][c4] = x0;
    *(float4*)&xr[1][nl][c4] = *(const float4*)(X1 + o);
    *(float4*)&xr[2][nl][c4] = make_float4(2.f * s.x - x0.x, 2.f * s.y - x0.y,
                                           2.f * s.z - x0.z, 2.f * s.w - x0.w);
  }
  __syncthreads();
  const int nl = tid >> 3, og = tid & 7, o0 = og * 16;
  float acc[16];
#pragma unroll
  for (int j = 0; j < 16; ++j) acc[j] = b_ru[o0 + j];
  for (int c = 0; c < 66; ++c) {
    int f = (c < 64) ? (c + 2) : (c - 64);
    const float* wr = w_ru + (size_t)(f * 3) * 128 + o0;
#pragma unroll
    for (int m = 0; m < 3; ++m) {
      float xv = xr[m][nl][c];
      float wl[16];
      *(float4*)(wl)      = *(const float4*)(wr + m * 128);
      *(float4*)(wl + 4)  = *(const float4*)(wr + m * 128 + 4);
      *(float4*)(wl + 8)  = *(const float4*)(wr + m * 128 + 8);
      *(float4*)(wl + 12) = *(const float4*)(wr + m * 128 + 12);
#pragma unroll
      for (int j = 0; j < 16; ++j) acc[j] += xv * wl[j];
    }
  }
  const int n = n0 + nl;
  const float dv = dinv[n];
  if (og < 4) {
#pragma unroll
    for (int j = 0; j < 16; ++j) {
      int o = o0 + j;
      float r = 1.f / (1.f + expf(-acc[j]));
      float rh = r * hx[n * 64 + o];
      X0w[(size_t)n * CST + o] = rh;
      float srh = dv * rh;
      XS0w[(size_t)n * CST + o] = srh;
      rhq[nl][o] = srh;
    }
  } else {
#pragma unroll
    for (int j = 0; j < 16; ++j)
      UG[n * 64 + (o0 - 64) + j] = 1.f / (1.f + expf(-acc[j]));
  }
  __syncthreads();
  for (int p = tid; p < 5 * 64; p += 256) {
    int nt = p >> 6, l = p & 63;
    short8v o8;
#pragma unroll
    for (int j = 0; j < 8; ++j) {
      int nloc = 8 * (l >> 4) + j;
      int nn = n0 + nloc;
      int c = nt * 16 + (l & 15);
      float v;
      if (c < 64)      v = rhq[nloc][c];
      else if (c < 66) v = dinv[nn] * inp[nn * 2 + (c - 64)];
      else             v = 0.f;
      o8[j] = (short)f2bf(v);
    }
    *(short8v*)(UtF + ((size_t)blockIdx.x * 5 + nt) * 512 + l * 8) = o8;
  }
}

// ---------------- final (epiB fused): candidate + output ---------------------
__global__ __launch_bounds__(256) void k_final(const float* __restrict__ P,
    const float* __restrict__ XS1,
    const float* __restrict__ X0, const float* __restrict__ X1,
    const float* __restrict__ w_c, const float* __restrict__ b_c,
    const float* __restrict__ hx, const float* __restrict__ UG,
    float* __restrict__ out) {
  __shared__ float xr[3][16][68];
  const int n0 = blockIdx.x * 16;
  const int tid = threadIdx.x;
  for (int p = tid; p < 16 * 17; p += 256) {
    int nl = p / 17, c4 = (p % 17) * 4;
    size_t o = (size_t)(n0 + nl) * CST + c4;
    float4 x0 = *(const float4*)(X0 + o);
    float4 s  = *(const float4*)(XS1 + o);
#pragma unroll
    for (int sp = 0; sp < SPLITS; ++sp) {
      float4 t = *(const float4*)(P + (size_t)sp * NS + o);
      s.x += t.x; s.y += t.y; s.z += t.z; s.w += t.w;
    }
    *(float4*)&xr[0][nl][c4] = x0;
    *(float4*)&xr[1][nl][c4] = *(const float4*)(X1 + o);
    *(float4*)&xr[2][nl][c4] = make_float4(2.f * s.x - x0.x, 2.f * s.y - x0.y,
                                           2.f * s.z - x0.z, 2.f * s.w - x0.w);
  }
  __syncthreads();
  const int nl = tid >> 4, ot = tid & 15, o0 = ot * 4;
  float acc[4];
#pragma unroll
  for (int j = 0; j < 4; ++j) acc[j] = b_c[o0 + j];
  for (int c = 0; c < 66; ++c) {
    int f = (c < 64) ? (c + 2) : (c - 64);
#pragma unroll
    for (int m = 0; m < 3; ++m) {
      float xv = xr[m][nl][c];
      float wl[4];
      *(float4*)(wl) = *(const float4*)(w_c + (size_t)(f * 3 + m) * 64 + o0);
#pragma unroll
      for (int j = 0; j < 4; ++j) acc[j] += xv * wl[j];
    }
  }
  const int n = n0 + nl;
#pragma unroll
  for (int j = 0; j < 4; ++j) {
    int o = o0 + j;
    float cc = tanhf(acc[j]);
    float u = UG[n * 64 + o];
    float h = hx[n * 64 + o];
    out[n * 64 + o] = u * h + (1.f - u) * cc;
  }
}

// ---------------- launcher ----------------------------------------------------
extern "C" void kernel_launch(void* const* d_in, const int* in_sizes, int n_in,
                              void* d_out, int out_size, void* d_ws, size_t ws_size,
                              hipStream_t stream) {
  const float* inp  = (const float*)d_in[0];
  const float* hx   = (const float*)d_in[1];
  const float* adj  = (const float*)d_in[2];
  const float* w_ru = (const float*)d_in[3];
  const float* b_ru = (const float*)d_in[4];
  const float* w_c  = (const float*)d_in[5];
  const float* b_c  = (const float*)d_in[6];
  float* out = (float*)d_out;

  float* ws    = (float*)d_ws;
  float* dinv  = ws;                       // 8192
  float* dpart = ws + 8192;                // 4*8192
  float* X0    = ws + 8192 + 4 * 8192;     // [N][80] each
  float* XS0   = X0 + NS;
  float* X1    = XS0 + NS;
  float* XS1   = X1 + NS;
  float* P     = XS1 + NS;                 // SPLITS * NS
  ushort* UtF  = (ushort*)(P + (size_t)SPLITS * NS);       // 1.25 MB
  ushort* adjF = UtF + (size_t)KBT * 5 * 512;              // 128 MB
  float* UG    = (float*)(adjF + (size_t)512 * KBT * 512); // [N][64] (also OOB pad)

  dim3 cg(KBT, MCH);
  dim3 gg(NN / 64, SPLITS);

  k_conv <<<cg, 256, 0, stream>>>(adj, adjF, dpart);
  k_build<<<NN / 32, 256, 0, stream>>>(hx, inp, dpart, dinv, X0, XS0, UtF);

  // gconv 1 (gates)
  k_gemm <<<gg, 256, 0, stream>>>(adjF, UtF, P);
  k_epiA <<<NN / 32, 512, 0, stream>>>(P, XS0, dinv, X1, XS1, UtF);
  k_gemm <<<gg, 256, 0, stream>>>(adjF, UtF, P);
  k_gates<<<NN / 32, 256, 0, stream>>>(P, XS1, X0, X1, w_ru, b_ru, hx, inp, dinv,
                                       X0, XS0, UtF, UG);

  // gconv 2 (candidate)
  k_gemm <<<gg, 256, 0, stream>>>(adjF, UtF, P);
  k_epiA <<<NN / 32, 512, 0, stream>>>(P, XS0, dinv, X1, XS1, UtF);
  k_gemm <<<gg, 256, 0, stream>>>(adjF, UtF, P);
  k_final<<<NN / 16, 256, 0, stream>>>(P, XS1, X0, X1, w_c, b_c, hx, UG, out);
}